// Round 2
// baseline (2209.114 us; speedup 1.0000x reference)
//
#include <hip/hip_runtime.h>

#define H 8
#define C 16
#define HC 128          // H*C
#define NEG 0.2f

__device__ __forceinline__ float lrelu(float x) { return x > 0.f ? x : NEG * x; }

// order-preserving float<->uint mapping for atomicMax on floats
__device__ __forceinline__ unsigned fenc(float f) {
    unsigned b = __float_as_uint(f);
    return (b & 0x80000000u) ? ~b : (b | 0x80000000u);
}
__device__ __forceinline__ float fdec(unsigned u) {
    unsigned b = (u & 0x80000000u) ? (u & 0x7fffffffu) : ~u;
    return __uint_as_float(b);
}

// K1: h = x @ W (fp32), plus per-node attention logits a_src/a_dst and
// amax seeded with the self-loop alpha. One block (128 threads) per node.
__global__ void k1_gemm(const float* __restrict__ x,
                        const float* __restrict__ W,
                        const float* __restrict__ att_src,
                        const float* __restrict__ att_dst,
                        float* __restrict__ h,
                        float* __restrict__ a_src,
                        float* __restrict__ a_dst,
                        unsigned* __restrict__ amax_enc) {
    __shared__ float xs[HC];
    __shared__ float hs[HC];
    const int n = blockIdx.x;
    const int t = threadIdx.x;
    xs[t] = x[(size_t)n * HC + t];
    __syncthreads();
    float acc = 0.f;
#pragma unroll 8
    for (int k = 0; k < HC; ++k)
        acc += xs[k] * W[k * HC + t];   // W col t; W is 64 KB, L2-resident
    h[(size_t)n * HC + t] = acc;
    hs[t] = acc;
    __syncthreads();
    if (t < H) {
        float s = 0.f, d = 0.f;
#pragma unroll
        for (int c = 0; c < C; ++c) {
            float hv = hs[t * C + c];
            s += hv * att_src[t * C + c];
            d += hv * att_dst[t * C + c];
        }
        a_src[n * H + t] = s;
        a_dst[n * H + t] = d;
        amax_enc[n * H + t] = fenc(lrelu(s + d));  // self-loop seeds the max
    }
}

// K2: segment max over edges. One thread per (edge, head).
__global__ void k2_max(const int* __restrict__ ei,
                       const float* __restrict__ a_src,
                       const float* __restrict__ a_dst,
                       unsigned* __restrict__ amax_enc,
                       int E) {
    unsigned g = blockIdx.x * blockDim.x + threadIdx.x;
    if (g >= (unsigned)E * H) return;
    int e = g >> 3, hd = g & 7;
    int src = ei[e], dst = ei[E + e];
    float alpha = lrelu(a_src[src * H + hd] + a_dst[dst * H + hd]);
    atomicMax(&amax_enc[dst * H + hd], fenc(alpha));
}

// K3: decode amax in place to float; init denom with the self-loop term.
__global__ void k3_node(const float* __restrict__ a_src,
                        const float* __restrict__ a_dst,
                        float* __restrict__ amax,   // in: encoded uint, out: float
                        float* __restrict__ denom,
                        int NH) {
    int g = blockIdx.x * blockDim.x + threadIdx.x;
    if (g >= NH) return;
    float m = fdec(((const unsigned*)amax)[g]);
    amax[g] = m;
    denom[g] = __expf(lrelu(a_src[g] + a_dst[g]) - m);
}

// K4: fused edge pass — unnormalized message accumulation + denom sum.
// One thread per (edge, h*16+c); 128 consecutive threads share one edge.
__global__ void k4_acc(const int* __restrict__ ei,
                       const float* __restrict__ a_src,
                       const float* __restrict__ a_dst,
                       const float* __restrict__ amax,
                       const float* __restrict__ h,
                       float* __restrict__ denom,
                       float* __restrict__ acc,
                       int E) {
    unsigned g = blockIdx.x * blockDim.x + threadIdx.x;
    if (g >= (unsigned)E * HC) return;          // 409.6M < 2^32
    unsigned e = g >> 7;
    int t = g & 127;
    int hd = t >> 4;
    int src = ei[e], dst = ei[E + e];
    float ex = __expf(lrelu(a_src[src * H + hd] + a_dst[dst * H + hd])
                      - amax[dst * H + hd]);
    atomicAdd(&acc[(size_t)dst * HC + t], h[(size_t)src * HC + t] * ex);
    if ((t & 15) == 0) atomicAdd(&denom[dst * H + hd], ex);
}

// K5: epilogue — add self-loop message, normalize, add bias.
__global__ void k5_out(const float* __restrict__ acc,
                       const float* __restrict__ h,
                       const float* __restrict__ a_src,
                       const float* __restrict__ a_dst,
                       const float* __restrict__ amax,
                       const float* __restrict__ denom,
                       const float* __restrict__ bias,
                       float* __restrict__ out,
                       int NHC) {
    int g = blockIdx.x * blockDim.x + threadIdx.x;
    if (g >= NHC) return;
    int t = g & 127, hd = t >> 4;
    int nh = (g >> 7) * H + hd;
    float ex_self = __expf(lrelu(a_src[nh] + a_dst[nh]) - amax[nh]);
    float val = (acc[g] + h[g] * ex_self) / (denom[nh] + 1e-16f) + bias[t];
    out[g] = val;
}

extern "C" void kernel_launch(void* const* d_in, const int* in_sizes, int n_in,
                              void* d_out, int out_size, void* d_ws, size_t ws_size,
                              hipStream_t stream) {
    const float* x       = (const float*)d_in[0];
    const int*   ei      = (const int*)d_in[1];
    const float* W       = (const float*)d_in[2];
    const float* att_src = (const float*)d_in[3];
    const float* att_dst = (const float*)d_in[4];
    const float* bias    = (const float*)d_in[5];
    float* out = (float*)d_out;

    const int N = in_sizes[0] / HC;
    const int E = in_sizes[1] / 2;

    // workspace layout (fp32): h[N*128] | acc[N*128] | a_src[N*8] | a_dst[N*8]
    //                          | amax[N*8] | denom[N*8]   (~115 MB total)
    float* h_ws   = (float*)d_ws;
    float* acc    = h_ws + (size_t)N * HC;
    float* a_src  = acc  + (size_t)N * HC;
    float* a_dst  = a_src + (size_t)N * H;
    float* amax   = a_dst + (size_t)N * H;
    float* denom  = amax + (size_t)N * H;

    hipMemsetAsync(acc, 0, (size_t)N * HC * sizeof(float), stream);

    k1_gemm<<<N, HC, 0, stream>>>(x, W, att_src, att_dst, h_ws, a_src, a_dst,
                                  (unsigned*)amax);

    unsigned t2 = (unsigned)E * H;
    k2_max<<<(t2 + 255) / 256, 256, 0, stream>>>(ei, a_src, a_dst,
                                                 (unsigned*)amax, E);

    int t3 = N * H;
    k3_node<<<(t3 + 255) / 256, 256, 0, stream>>>(a_src, a_dst, amax, denom, t3);

    unsigned long long t4 = (unsigned long long)E * HC;
    k4_acc<<<(unsigned)((t4 + 255) / 256), 256, 0, stream>>>(ei, a_src, a_dst,
                                                             amax, h_ws, denom,
                                                             acc, E);

    int t5 = N * HC;
    k5_out<<<(t5 + 255) / 256, 256, 0, stream>>>(acc, h_ws, a_src, a_dst, amax,
                                                 denom, bias, out, t5);
}

// Round 3
// 891.247 us; speedup vs baseline: 2.4787x; 2.4787x over previous
//
#include <hip/hip_runtime.h>

#define H 8
#define C 16
#define HC 128          // H*C
#define NEG 0.2f
#define SCAN_B 256

__device__ __forceinline__ float lrelu(float x) { return x > 0.f ? x : NEG * x; }

// K1: h = x @ W (fp32), plus per-node attention logits a_src/a_dst.
// One block (128 threads) per node.
__global__ void k1_gemm(const float* __restrict__ x,
                        const float* __restrict__ W,
                        const float* __restrict__ att_src,
                        const float* __restrict__ att_dst,
                        float* __restrict__ h,
                        float* __restrict__ a_src,
                        float* __restrict__ a_dst) {
    __shared__ float xs[HC];
    __shared__ float hs[HC];
    const int n = blockIdx.x;
    const int t = threadIdx.x;
    xs[t] = x[(size_t)n * HC + t];
    __syncthreads();
    float acc = 0.f;
#pragma unroll 8
    for (int k = 0; k < HC; ++k)
        acc += xs[k] * W[k * HC + t];   // W col t; 64 KB, L1/L2-resident
    h[(size_t)n * HC + t] = acc;
    hs[t] = acc;
    __syncthreads();
    if (t < H) {
        float s = 0.f, d = 0.f;
#pragma unroll
        for (int c = 0; c < C; ++c) {
            float hv = hs[t * C + c];
            s += hv * att_src[t * C + c];
            d += hv * att_dst[t * C + c];
        }
        a_src[n * H + t] = s;
        a_dst[n * H + t] = d;
    }
}

// ---- CSR build (by destination) ----

__global__ void kc_count(const int* __restrict__ ei, int* __restrict__ deg, int E) {
    int e = blockIdx.x * blockDim.x + threadIdx.x;
    if (e >= E) return;
    atomicAdd(&deg[ei[E + e]], 1);
}

// block-level inclusive scan of degree chunks
__global__ void ks_chunk(const int* __restrict__ deg, int* __restrict__ incl,
                         int* __restrict__ bsum, int N) {
    __shared__ int s[SCAN_B];
    int g = blockIdx.x * SCAN_B + threadIdx.x;
    s[threadIdx.x] = (g < N) ? deg[g] : 0;
    __syncthreads();
    for (int off = 1; off < SCAN_B; off <<= 1) {
        int v = (threadIdx.x >= off) ? s[threadIdx.x - off] : 0;
        __syncthreads();
        s[threadIdx.x] += v;
        __syncthreads();
    }
    if (g < N) incl[g] = s[threadIdx.x];
    if (threadIdx.x == SCAN_B - 1) bsum[blockIdx.x] = s[SCAN_B - 1];
}

// single-block inclusive scan of the (<=512) block sums
__global__ void ks_bsum(int* __restrict__ bsum, int nb) {
    __shared__ int s[512];
    int t = threadIdx.x;
    s[t] = (t < nb) ? bsum[t] : 0;
    __syncthreads();
    for (int off = 1; off < 512; off <<= 1) {
        int v = (t >= off) ? s[t - off] : 0;
        __syncthreads();
        s[t] += v;
        __syncthreads();
    }
    if (t < nb) bsum[t] = s[t];
}

// rowptr[g+1] = global inclusive prefix at g; rowptr[0] = 0
__global__ void ks_rowptr(const int* __restrict__ incl, const int* __restrict__ bsum,
                          int* __restrict__ rowptr, int N) {
    int g = blockIdx.x * SCAN_B + threadIdx.x;
    if (g == 0) rowptr[0] = 0;
    if (g < N) {
        int off = (blockIdx.x == 0) ? 0 : bsum[blockIdx.x - 1];
        rowptr[g + 1] = incl[g] + off;
    }
}

__global__ void kc_scatter(const int* __restrict__ ei, const int* __restrict__ rowptr,
                           int* __restrict__ cursor, int* __restrict__ col, int E) {
    int e = blockIdx.x * blockDim.x + threadIdx.x;
    if (e >= E) return;
    int dst = ei[E + e], src = ei[e];
    int pos = atomicAdd(&cursor[dst], 1);
    col[rowptr[dst] + pos] = src;
}

// K_PULL: one block (128 threads) per destination node. Online softmax over
// in-edges + self loop, register accumulation, single coalesced write.
__global__ void __launch_bounds__(128) k_pull(const int* __restrict__ rowptr,
                                              const int* __restrict__ col,
                                              const float* __restrict__ a_src,
                                              const float* __restrict__ a_dst,
                                              const float* __restrict__ h,
                                              const float* __restrict__ bias,
                                              float* __restrict__ out, int N) {
    __shared__ int cs[128];
    const int n = blockIdx.x;
    const int t = threadIdx.x;
    const int hd = t >> 4;
    const float ad = a_dst[n * H + hd];
    // self-loop seeds the online-softmax state
    float m = lrelu(a_src[n * H + hd] + ad);
    float s = 1.f;
    float acc = h[(size_t)n * HC + t];
    const int beg = rowptr[n], end = rowptr[n + 1];
    for (int base = beg; base < end; base += 128) {
        int nn = min(128, end - base);
        __syncthreads();
        if (t < nn) cs[t] = col[base + t];
        __syncthreads();
        for (int j = 0; j < nn; ++j) {
            int src = cs[j];
            float alpha = lrelu(a_src[src * H + hd] + ad);
            float mn = fmaxf(m, alpha);
            float corr = __expf(m - mn);
            float e = __expf(alpha - mn);
            float hv = h[(size_t)src * HC + t];
            s = s * corr + e;
            acc = acc * corr + hv * e;
            m = mn;
        }
    }
    out[(size_t)n * HC + t] = acc / (s + 1e-16f) + bias[t];
}

extern "C" void kernel_launch(void* const* d_in, const int* in_sizes, int n_in,
                              void* d_out, int out_size, void* d_ws, size_t ws_size,
                              hipStream_t stream) {
    const float* x       = (const float*)d_in[0];
    const int*   ei      = (const int*)d_in[1];
    const float* W       = (const float*)d_in[2];
    const float* att_src = (const float*)d_in[3];
    const float* att_dst = (const float*)d_in[4];
    const float* bias    = (const float*)d_in[5];
    float* out = (float*)d_out;

    const int N = in_sizes[0] / HC;
    const int E = in_sizes[1] / 2;
    const int nb = (N + SCAN_B - 1) / SCAN_B;   // 391 for N=100k (<=512 req'd)

    // workspace layout: h[N*128]f | a_src[N*8]f | a_dst[N*8]f | deg[N]i |
    //                   incl[N]i | bsum[nb]i | rowptr[N+1]i | cursor[N]i | col[E]i
    float* h_ws  = (float*)d_ws;
    float* a_src = h_ws + (size_t)N * HC;
    float* a_dst = a_src + (size_t)N * H;
    int* deg     = (int*)(a_dst + (size_t)N * H);
    int* incl    = deg + N;
    int* bsum    = incl + N;
    int* rowptr  = bsum + nb;
    int* cursor  = rowptr + (N + 1);
    int* col     = cursor + N;

    hipMemsetAsync(deg, 0, (size_t)N * sizeof(int), stream);
    hipMemsetAsync(cursor, 0, (size_t)N * sizeof(int), stream);

    k1_gemm<<<N, HC, 0, stream>>>(x, W, att_src, att_dst, h_ws, a_src, a_dst);

    kc_count<<<(E + 255) / 256, 256, 0, stream>>>(ei, deg, E);
    ks_chunk<<<nb, SCAN_B, 0, stream>>>(deg, incl, bsum, N);
    ks_bsum<<<1, 512, 0, stream>>>(bsum, nb);
    ks_rowptr<<<nb, SCAN_B, 0, stream>>>(incl, bsum, rowptr, N);
    kc_scatter<<<(E + 255) / 256, 256, 0, stream>>>(ei, rowptr, cursor, col, E);

    k_pull<<<N, HC, 0, stream>>>(rowptr, col, a_src, a_dst, h_ws, bias, out, N);
}